// Round 2
// baseline (64424.084 us; speedup 1.0000x reference)
//
#include <hip/hip_runtime.h>
#include <hip/hip_bf16.h>
#include <stdint.h>

// Problem: IN=512, H=2048, OUT=512, T=8192. Gate rows 4H=8192.
// Persistent-RNN: 256 blocks x 256 threads, 1 block/CU, W_ih||W_hh held in
// VGPRs as bf16 pairs. h exchanged device-wide as step-tagged u64 slices
// ({bf16 pair | step tag} in one relaxed agent-scope atomic) via L3.

// ---------------- helpers ----------------

__device__ __forceinline__ uint32_t packbf(float a, float b) {
    // round-to-nearest-even bf16 pack: a -> low16, b -> high16
    uint32_t ua = __float_as_uint(a);
    uint32_t ub = __float_as_uint(b);
    ua = (ua + 0x7fffu + ((ua >> 16) & 1u)) >> 16;
    ub = (ub + 0x7fffu + ((ub >> 16) & 1u)) >> 16;
    return ua | (ub << 16);
}

__device__ __forceinline__ float dot2bf(uint32_t a, uint32_t b, float c) {
    float d;
    asm("v_dot2_f32_bf16 %0, %1, %2, %3" : "=v"(d) : "v"(a), "v"(b), "v"(c));
    return d;
}

__device__ __forceinline__ float sigm(float x) { return 1.f / (1.f + __expf(-x)); }
__device__ __forceinline__ float tanh_fast(float x) { return 1.f - 2.f / (1.f + __expf(2.f * x)); }

// ---------------- kernel 0: invalidate hbuf tags ----------------
__global__ __launch_bounds__(256) void init_hbuf(unsigned long long* hbuf) {
    int i = blockIdx.x * 256 + threadIdx.x;
    if (i < 2048) hbuf[i] = ~0ull;  // tag 0xFFFFFFFF never matches a step index
}

// ---------------- kernel 1: persistent LSTM recurrence (input GEMM fused) ----------------
// Block b owns h indices [8b, 8b+8). Wave q computes gate type q (rows q*2048+8b+j).
// Combined vector v_t = [x_t | h_{t-1}] = 1280 bf16 pairs in LDS; lane owns pairs
// {k*64+lane : k in [0,20)}. Weights: 160 packed bf16 VGPRs/lane.
__global__ __launch_bounds__(256, 1) void lstm_persist(const float* __restrict__ seq,
                                                       const float* __restrict__ Wih,
                                                       const float* __restrict__ Whh,
                                                       const float* __restrict__ bih,
                                                       const float* __restrict__ bhh,
                                                       const float* __restrict__ h0,
                                                       const float* __restrict__ c0,
                                                       unsigned long long* hbuf,
                                                       float* __restrict__ hf32) {
    const int b = blockIdx.x, tid = threadIdx.x;
    const int q = tid >> 6, lane = tid & 63;
    const int hb = b * 8;

    // ---- preload [W_ih | W_hh] slice into registers (bf16 packed) ----
    uint32_t w[160];
#pragma unroll
    for (int j = 0; j < 8; j++) {
        const int row = q * 2048 + hb + j;
        const float2* rih = (const float2*)(Wih + (size_t)row * 512);
        const float2* rhh = (const float2*)(Whh + (size_t)row * 2048);
#pragma unroll
        for (int k = 0; k < 4; k++) {
            float2 v = rih[k * 64 + lane];
            w[j * 20 + k] = packbf(v.x, v.y);
        }
#pragma unroll
        for (int k = 4; k < 20; k++) {
            float2 v = rhh[(k - 4) * 64 + lane];
            w[j * 20 + k] = packbf(v.x, v.y);
        }
    }

    __shared__ uint32_t v_stage[1280];  // [0,256): x_t pairs; [256,1280): h_{t-1} pairs
    __shared__ float g_lds[32];

    // per-row bias + c state (wave 0, lanes 0..7)
    float bi = 0.f, bf = 0.f, bg = 0.f, bo = 0.f, c_state = 0.f;
    if (q == 0 && lane < 8) {
        const int r = hb + lane;
        bi = bih[r] + bhh[r];
        bf = bih[2048 + r] + bhh[2048 + r];
        bg = bih[4096 + r] + bhh[4096 + r];
        bo = bih[6144 + r] + bhh[6144 + r];
        c_state = c0[r];
    }

    // publish h0 slice with tag 0 (parity 0)
    if (q == 0 && lane < 4) {
        float a = h0[hb + lane * 2], b2 = h0[hb + lane * 2 + 1];
        unsigned long long v = ((unsigned long long)packbf(a, b2) << 32);
        __hip_atomic_store(&hbuf[b * 4 + lane], v, __ATOMIC_RELAXED, __HIP_MEMORY_SCOPE_AGENT);
    }

    // prefetch x_0: thread tid owns x pair tid (cols 2*tid, 2*tid+1)
    float2 xv = ((const float2*)seq)[tid];
    int gave_up = 0;

    for (int s = 1; s <= 8192; s++) {
        const int t = s - 1;
        // stage x_t (safe: everyone is past B2 of previous iter)
        v_stage[tid] = packbf(xv.x, xv.y);
        // prefetch x_{t+1} (independent of h; hides L2/L3 latency)
        if (s < 8192) xv = ((const float2*)(seq + (size_t)s * 512))[tid];

        // wave 0 spins for all 1024 tagged h pairs of step t -> LDS
        if (q == 0 && !gave_up) {
            const unsigned long long* hp = hbuf + ((t & 1) << 10);
            const uint32_t want = (uint32_t)t;
            uint32_t got = 0;
            int tries = 0;
            while (got != 0xffffu) {
#pragma unroll
                for (int i = 0; i < 16; i++) {
                    if (!((got >> i) & 1u)) {
                        unsigned long long v = __hip_atomic_load(&hp[i * 64 + lane],
                                                                 __ATOMIC_RELAXED, __HIP_MEMORY_SCOPE_AGENT);
                        if ((uint32_t)v == want) {
                            v_stage[256 + i * 64 + lane] = (uint32_t)(v >> 32);
                            got |= (1u << i);
                        }
                    }
                }
                if (++tries > (1 << 20)) { gave_up = 1; break; }  // diagnostic fuse, never trips when healthy
            }
        }
        __syncthreads();  // B1: v_stage ready

        // ---- dot: 8 rows x 20 pairs per lane, bf16 dot2, fp32 accum ----
        float acc[8] = {0.f, 0.f, 0.f, 0.f, 0.f, 0.f, 0.f, 0.f};
#pragma unroll
        for (int k = 0; k < 20; k++) {
            uint32_t hv = v_stage[k * 64 + lane];
#pragma unroll
            for (int j = 0; j < 8; j++) acc[j] = dot2bf(w[j * 20 + k], hv, acc[j]);
        }
        // butterfly reduce each row across 64 lanes
#pragma unroll
        for (int off = 32; off; off >>= 1) {
#pragma unroll
            for (int j = 0; j < 8; j++) acc[j] += __shfl_xor(acc[j], off, 64);
        }
#pragma unroll
        for (int j = 0; j < 8; j++)
            if (lane == j) g_lds[(q << 3) + j] = acc[j];
        __syncthreads();  // B2: all 32 gate sums ready

        if (q == 0) {
            float hval = 0.f;
            if (lane < 8) {
                float gi = g_lds[lane] + bi;
                float gf = g_lds[8 + lane] + bf;
                float gg = g_lds[16 + lane] + bg;
                float go = g_lds[24 + lane] + bo;
                float i_ = sigm(gi), f_ = sigm(gf), g_ = tanh_fast(gg), o_ = sigm(go);
                c_state = f_ * c_state + i_ * g_;
                hval = o_ * tanh_fast(c_state);
                if (s == 8192) hf32[hb + lane] = hval;
            }
            // lanes 0..3 gather pairs from lanes 0..7, publish tagged slices
            float ha = __shfl(hval, (lane & 3) * 2, 64);
            float hb2 = __shfl(hval, (lane & 3) * 2 + 1, 64);
            if (lane < 4) {
                unsigned long long v = ((unsigned long long)packbf(ha, hb2) << 32) | (uint32_t)s;
                __hip_atomic_store(&hbuf[((s & 1) << 10) + b * 4 + lane], v,
                                   __ATOMIC_RELAXED, __HIP_MEMORY_SCOPE_AGENT);
            }
        }
    }
}

// ---------------- kernel 2: pred = h_last @ W_lin^T + b_lin ----------------
__global__ __launch_bounds__(256) void final_linear(const float* __restrict__ hf,
                                                    const float* __restrict__ Wlin,
                                                    const float* __restrict__ blin,
                                                    float* __restrict__ out) {
    const int row = blockIdx.x * 4 + (threadIdx.x >> 6);
    const int lane = threadIdx.x & 63;
    float acc = 0.f;
#pragma unroll
    for (int it = 0; it < 8; it++) {
        int c = it * 256 + lane * 4;
        float4 wv = *(const float4*)&Wlin[(size_t)row * 2048 + c];
        float4 hv = *(const float4*)&hf[c];
        acc += wv.x * hv.x + wv.y * hv.y + wv.z * hv.z + wv.w * hv.w;
    }
#pragma unroll
    for (int off = 32; off; off >>= 1) acc += __shfl_xor(acc, off, 64);
    if (lane == 0) out[row] = acc + blin[row];
}

// ---------------- launch ----------------
extern "C" void kernel_launch(void* const* d_in, const int* in_sizes, int n_in,
                              void* d_out, int out_size, void* d_ws, size_t ws_size,
                              hipStream_t stream) {
    const float* seq  = (const float*)d_in[0];
    const float* Wih  = (const float*)d_in[1];
    const float* Whh  = (const float*)d_in[2];
    const float* bih  = (const float*)d_in[3];
    const float* bhh  = (const float*)d_in[4];
    const float* h0   = (const float*)d_in[5];
    const float* c0   = (const float*)d_in[6];
    const float* Wlin = (const float*)d_in[7];
    const float* blin = (const float*)d_in[8];
    float* out = (float*)d_out;

    char* ws = (char*)d_ws;
    unsigned long long* hbuf = (unsigned long long*)ws;  // 2*1024*8 = 16 KiB
    float* hf32 = (float*)(ws + 16384);                  // 8 KiB

    init_hbuf<<<8, 256, 0, stream>>>(hbuf);
    lstm_persist<<<256, 256, 0, stream>>>(seq, Wih, Whh, bih, bhh, h0, c0, hbuf, hf32);
    final_linear<<<128, 256, 0, stream>>>(hf32, Wlin, blin, out);
}

// Round 3
// 19448.724 us; speedup vs baseline: 3.3125x; 3.3125x over previous
//
#include <hip/hip_runtime.h>
#include <hip/hip_bf16.h>
#include <stdint.h>

// Problem: IN=512, H=2048, OUT=512, T=8192. Gate rows 4H=8192.
// Persistent-RNN: 256 blocks x 256 threads, 1 block/CU, [W_ih|W_hh] held in
// VGPRs as bf16 pairs. h exchanged device-wide as step-tagged u64 slices
// ({bf16 pair | step tag} in one relaxed agent-scope atomic) via L3.
// Round 3: branchless 4-wave parallel spin (was: 16 serialized L3 round
// trips per sweep in conditional basic blocks); 10-shuffle multi-row fold
// reduction (was 48 shuffles).

// ---------------- helpers ----------------

__device__ __forceinline__ uint32_t packbf(float a, float b) {
    // round-to-nearest-even bf16 pack: a -> low16, b -> high16
    uint32_t ua = __float_as_uint(a);
    uint32_t ub = __float_as_uint(b);
    ua = (ua + 0x7fffu + ((ua >> 16) & 1u)) >> 16;
    ub = (ub + 0x7fffu + ((ub >> 16) & 1u)) >> 16;
    return ua | (ub << 16);
}

__device__ __forceinline__ float dot2bf(uint32_t a, uint32_t b, float c) {
    float d;
    asm("v_dot2_f32_bf16 %0, %1, %2, %3" : "=v"(d) : "v"(a), "v"(b), "v"(c));
    return d;
}

__device__ __forceinline__ float sigm(float x) { return 1.f / (1.f + __expf(-x)); }
__device__ __forceinline__ float tanh_fast(float x) { return 1.f - 2.f / (1.f + __expf(2.f * x)); }

// ---------------- kernel 0: invalidate hbuf tags ----------------
__global__ __launch_bounds__(256) void init_hbuf(unsigned long long* hbuf) {
    int i = blockIdx.x * 256 + threadIdx.x;
    if (i < 2048) hbuf[i] = ~0ull;  // tag 0xFFFFFFFF never matches a step index
}

// ---------------- kernel 1: persistent LSTM recurrence (input GEMM fused) ----------------
// Block b owns h indices [8b, 8b+8). Wave q computes gate type q (rows q*2048+8b+j).
// Combined vector v_t = [x_t | h_{t-1}] = 1280 bf16 pairs in LDS; lane owns pairs
// {k*64+lane : k in [0,20)}. Weights: 160 packed bf16 VGPRs/lane.
// Spin: wave q watches h pairs [256q, 256q+256) — 4 unconditional u64 loads per
// sweep, all in flight together; idempotent LDS re-store; exit via __all().
__global__ __launch_bounds__(256, 1) void lstm_persist(const float* __restrict__ seq,
                                                       const float* __restrict__ Wih,
                                                       const float* __restrict__ Whh,
                                                       const float* __restrict__ bih,
                                                       const float* __restrict__ bhh,
                                                       const float* __restrict__ h0,
                                                       const float* __restrict__ c0,
                                                       unsigned long long* hbuf,
                                                       float* __restrict__ hf32) {
    const int b = blockIdx.x, tid = threadIdx.x;
    const int q = tid >> 6, lane = tid & 63;
    const int hb = b * 8;

    // ---- preload [W_ih | W_hh] slice into registers (bf16 packed) ----
    uint32_t w[160];
#pragma unroll
    for (int j = 0; j < 8; j++) {
        const int row = q * 2048 + hb + j;
        const float2* rih = (const float2*)(Wih + (size_t)row * 512);
        const float2* rhh = (const float2*)(Whh + (size_t)row * 2048);
#pragma unroll
        for (int k = 0; k < 4; k++) {
            float2 v = rih[k * 64 + lane];
            w[j * 20 + k] = packbf(v.x, v.y);
        }
#pragma unroll
        for (int k = 4; k < 20; k++) {
            float2 v = rhh[(k - 4) * 64 + lane];
            w[j * 20 + k] = packbf(v.x, v.y);
        }
    }

    __shared__ uint32_t v_stage[1280];  // [0,256): x_t pairs; [256,1280): h_{t-1} pairs
    __shared__ float g_lds[32];

    // per-row bias + c state (wave 0, lanes 0..7)
    float bi = 0.f, bf = 0.f, bg = 0.f, bo = 0.f, c_state = 0.f;
    if (q == 0 && lane < 8) {
        const int r = hb + lane;
        bi = bih[r] + bhh[r];
        bf = bih[2048 + r] + bhh[2048 + r];
        bg = bih[4096 + r] + bhh[4096 + r];
        bo = bih[6144 + r] + bhh[6144 + r];
        c_state = c0[r];
    }

    // publish h0 slice with tag 0 (parity 0)
    if (q == 0 && lane < 4) {
        float a = h0[hb + lane * 2], b2 = h0[hb + lane * 2 + 1];
        unsigned long long v = ((unsigned long long)packbf(a, b2) << 32);
        __hip_atomic_store(&hbuf[b * 4 + lane], v, __ATOMIC_RELAXED, __HIP_MEMORY_SCOPE_AGENT);
    }

    // prefetch x_0: thread tid owns x pair tid (cols 2*tid, 2*tid+1)
    float2 xv = ((const float2*)seq)[tid];
    int gave_up = 0;

    for (int s = 1; s <= 8192; s++) {
        const int t = s - 1;
        // stage x_t (safe: everyone is past B2 of previous iter)
        v_stage[tid] = packbf(xv.x, xv.y);
        // prefetch x_{t+1} (independent of h; hides L2/L3 latency)
        if (s < 8192) xv = ((const float2*)(seq + (size_t)s * 512))[tid];

        // ---- parallel branchless spin: wave q owns h pairs [256q, 256q+256) ----
        if (!gave_up) {
            const unsigned long long* hp = hbuf + ((t & 1) << 10) + q * 256 + lane;
            const uint32_t want = (uint32_t)t;
            int tries = 0;
            for (;;) {
                unsigned long long v0 = __hip_atomic_load(&hp[0],   __ATOMIC_RELAXED, __HIP_MEMORY_SCOPE_AGENT);
                unsigned long long v1 = __hip_atomic_load(&hp[64],  __ATOMIC_RELAXED, __HIP_MEMORY_SCOPE_AGENT);
                unsigned long long v2 = __hip_atomic_load(&hp[128], __ATOMIC_RELAXED, __HIP_MEMORY_SCOPE_AGENT);
                unsigned long long v3 = __hip_atomic_load(&hp[192], __ATOMIC_RELAXED, __HIP_MEMORY_SCOPE_AGENT);
                uint32_t* vs = &v_stage[256 + q * 256 + lane];
                vs[0]   = (uint32_t)(v0 >> 32);   // idempotent: payload fixed once tag matches
                vs[64]  = (uint32_t)(v1 >> 32);
                vs[128] = (uint32_t)(v2 >> 32);
                vs[192] = (uint32_t)(v3 >> 32);
                int ok = ((uint32_t)v0 == want) & ((uint32_t)v1 == want) &
                         ((uint32_t)v2 == want) & ((uint32_t)v3 == want);
                if (__all(ok)) break;
                if (++tries > (1 << 18)) { gave_up = 1; break; }  // diagnostic fuse
            }
        }
        __syncthreads();  // B1: v_stage ready (4 spinner waves joined)

        // ---- dot: 8 rows x 20 pairs per lane, bf16 dot2, fp32 accum ----
        float acc[8] = {0.f, 0.f, 0.f, 0.f, 0.f, 0.f, 0.f, 0.f};
#pragma unroll
        for (int k = 0; k < 20; k++) {
            uint32_t hv = v_stage[k * 64 + lane];
#pragma unroll
            for (int j = 0; j < 8; j++) acc[j] = dot2bf(w[j * 20 + k], hv, acc[j]);
        }

        // ---- multi-row fold reduction: 8 accs -> 1 (3 stages), then sum 3 stages ----
        // After folds, lane L holds row r(L) = 4*(L&1) + 2*((L>>1)&1) + ((L>>2)&1).
#pragma unroll
        for (int j = 0; j < 4; j++) {  // d=1: 8 -> 4
            float lo = acc[j], hi = acc[j + 4];
            float sel = (lane & 1) ? lo : hi;
            float got = __shfl_xor(sel, 1, 64);
            acc[j] = ((lane & 1) ? hi : lo) + got;
        }
#pragma unroll
        for (int j = 0; j < 2; j++) {  // d=2: 4 -> 2
            float lo = acc[j], hi = acc[j + 2];
            float sel = (lane & 2) ? lo : hi;
            float got = __shfl_xor(sel, 2, 64);
            acc[j] = ((lane & 2) ? hi : lo) + got;
        }
        {  // d=4: 2 -> 1
            float lo = acc[0], hi = acc[1];
            float sel = (lane & 4) ? lo : hi;
            float got = __shfl_xor(sel, 4, 64);
            acc[0] = ((lane & 4) ? hi : lo) + got;
        }
        acc[0] += __shfl_xor(acc[0], 8, 64);
        acc[0] += __shfl_xor(acc[0], 16, 64);
        acc[0] += __shfl_xor(acc[0], 32, 64);
        if (lane < 8) {
            const int row = 4 * (lane & 1) + 2 * ((lane >> 1) & 1) + ((lane >> 2) & 1);
            g_lds[(q << 3) + row] = acc[0];
        }
        __syncthreads();  // B2: all 32 gate sums ready

        if (q == 0) {
            float hval = 0.f;
            if (lane < 8) {
                float gi = g_lds[lane] + bi;
                float gf = g_lds[8 + lane] + bf;
                float gg = g_lds[16 + lane] + bg;
                float go = g_lds[24 + lane] + bo;
                float i_ = sigm(gi), f_ = sigm(gf), g_ = tanh_fast(gg), o_ = sigm(go);
                c_state = f_ * c_state + i_ * g_;
                hval = o_ * tanh_fast(c_state);
                if (s == 8192) hf32[hb + lane] = hval;
            }
            // lanes 0..3 gather pairs from lanes 0..7, publish tagged slices
            float ha = __shfl(hval, (lane & 3) * 2, 64);
            float hb2 = __shfl(hval, (lane & 3) * 2 + 1, 64);
            if (lane < 4) {
                unsigned long long v = ((unsigned long long)packbf(ha, hb2) << 32) | (uint32_t)s;
                __hip_atomic_store(&hbuf[((s & 1) << 10) + b * 4 + lane], v,
                                   __ATOMIC_RELAXED, __HIP_MEMORY_SCOPE_AGENT);
            }
        }
    }
}

// ---------------- kernel 2: pred = h_last @ W_lin^T + b_lin ----------------
__global__ __launch_bounds__(256) void final_linear(const float* __restrict__ hf,
                                                    const float* __restrict__ Wlin,
                                                    const float* __restrict__ blin,
                                                    float* __restrict__ out) {
    const int row = blockIdx.x * 4 + (threadIdx.x >> 6);
    const int lane = threadIdx.x & 63;
    float acc = 0.f;
#pragma unroll
    for (int it = 0; it < 8; it++) {
        int c = it * 256 + lane * 4;
        float4 wv = *(const float4*)&Wlin[(size_t)row * 2048 + c];
        float4 hv = *(const float4*)&hf[c];
        acc += wv.x * hv.x + wv.y * hv.y + wv.z * hv.z + wv.w * hv.w;
    }
#pragma unroll
    for (int off = 32; off; off >>= 1) acc += __shfl_xor(acc, off, 64);
    if (lane == 0) out[row] = acc + blin[row];
}

// ---------------- launch ----------------
extern "C" void kernel_launch(void* const* d_in, const int* in_sizes, int n_in,
                              void* d_out, int out_size, void* d_ws, size_t ws_size,
                              hipStream_t stream) {
    const float* seq  = (const float*)d_in[0];
    const float* Wih  = (const float*)d_in[1];
    const float* Whh  = (const float*)d_in[2];
    const float* bih  = (const float*)d_in[3];
    const float* bhh  = (const float*)d_in[4];
    const float* h0   = (const float*)d_in[5];
    const float* c0   = (const float*)d_in[6];
    const float* Wlin = (const float*)d_in[7];
    const float* blin = (const float*)d_in[8];
    float* out = (float*)d_out;

    char* ws = (char*)d_ws;
    unsigned long long* hbuf = (unsigned long long*)ws;  // 2*1024*8 = 16 KiB
    float* hf32 = (float*)(ws + 16384);                  // 8 KiB

    init_hbuf<<<8, 256, 0, stream>>>(hbuf);
    lstm_persist<<<256, 256, 0, stream>>>(seq, Wih, Whh, bih, bhh, h0, c0, hbuf, hf32);
    final_linear<<<128, 256, 0, stream>>>(hf32, Wlin, blin, out);
}

// Round 4
// 17466.307 us; speedup vs baseline: 3.6885x; 1.1135x over previous
//
#include <hip/hip_runtime.h>
#include <hip/hip_bf16.h>
#include <stdint.h>

// Problem: IN=512, H=2048, OUT=512, T=8192. Gate rows 4H=8192.
// Persistent-RNN: 256 blocks x 256 threads, 1 block/CU, [W_ih|W_hh] in VGPRs
// as bf16 pairs. h exchanged device-wide as step-tagged u64 slices
// ({bf16 pair | step tag} in one relaxed agent-scope atomic) via L3.
// Round 4: wave q owns rows {2q,2q+1} x all 4 gates -> per-wave gate math +
// per-wave publish (B2 and wave0 serialization removed; ONE barrier/step);
// parity double-buffered v_stage; 2-deep pipelined spin (halves detect quantum).

// ---------------- helpers ----------------

__device__ __forceinline__ uint32_t packbf(float a, float b) {
    // round-to-nearest-even bf16 pack: a -> low16, b -> high16
    uint32_t ua = __float_as_uint(a);
    uint32_t ub = __float_as_uint(b);
    ua = (ua + 0x7fffu + ((ua >> 16) & 1u)) >> 16;
    ub = (ub + 0x7fffu + ((ub >> 16) & 1u)) >> 16;
    return ua | (ub << 16);
}

__device__ __forceinline__ float dot2bf(uint32_t a, uint32_t b, float c) {
    float d;
    asm("v_dot2_f32_bf16 %0, %1, %2, %3" : "=v"(d) : "v"(a), "v"(b), "v"(c));
    return d;
}

__device__ __forceinline__ float sigm(float x) { return 1.f / (1.f + __expf(-x)); }
__device__ __forceinline__ float tanh_fast(float x) { return 1.f - 2.f / (1.f + __expf(2.f * x)); }

#define ALOAD(p) __hip_atomic_load((p), __ATOMIC_RELAXED, __HIP_MEMORY_SCOPE_AGENT)

// ---------------- kernel 0: invalidate hbuf tags ----------------
__global__ __launch_bounds__(256) void init_hbuf(unsigned long long* hbuf) {
    int i = blockIdx.x * 256 + threadIdx.x;
    if (i < 2048) hbuf[i] = ~0ull;  // tag 0xFFFFFFFF never matches a step index
}

// ---------------- kernel 1: persistent LSTM recurrence (input GEMM fused) ----------------
// Block b owns h indices [8b, 8b+8). Wave q owns rows {hb+2q, hb+2q+1}, ALL 4 gates.
// Combined vector v_t = [x_t | h_{t-1}] = 1280 bf16 pairs, parity double-buffered in LDS;
// lane owns pairs {k*64+lane : k in [0,20)}. Weights: 160 packed bf16 VGPRs/lane,
// combo c = gate*2 + rowbit, c in [0,8).
__global__ __launch_bounds__(256, 1) void lstm_persist(const float* __restrict__ seq,
                                                       const float* __restrict__ Wih,
                                                       const float* __restrict__ Whh,
                                                       const float* __restrict__ bih,
                                                       const float* __restrict__ bhh,
                                                       const float* __restrict__ h0,
                                                       const float* __restrict__ c0,
                                                       unsigned long long* hbuf,
                                                       float* __restrict__ hf32) {
    const int b = blockIdx.x, tid = threadIdx.x;
    const int q = tid >> 6, lane = tid & 63;
    const int hb = b * 8;
    const int rb = (lane >> 2) & 1;       // this lane's row within the wave's pair
    const int myrow = hb + 2 * q + rb;

    // ---- preload [W_ih | W_hh] rows for all 4 gates of rows {2q, 2q+1} ----
    uint32_t w[160];
#pragma unroll
    for (int c = 0; c < 8; c++) {
        const int R = (c >> 1) * 2048 + hb + 2 * q + (c & 1);
        const float2* rih = (const float2*)(Wih + (size_t)R * 512);
        const float2* rhh = (const float2*)(Whh + (size_t)R * 2048);
#pragma unroll
        for (int k = 0; k < 4; k++) {
            float2 v = rih[k * 64 + lane];
            w[c * 20 + k] = packbf(v.x, v.y);
        }
#pragma unroll
        for (int k = 4; k < 20; k++) {
            float2 v = rhh[(k - 4) * 64 + lane];
            w[c * 20 + k] = packbf(v.x, v.y);
        }
    }

    __shared__ uint32_t v_stage[2][1280];  // [0,256): x_t pairs; [256,1280): h_{t-1} pairs

    // per-lane (replicated) bias + c state for row `myrow`
    const float bi = bih[myrow] + bhh[myrow];
    const float bf_ = bih[2048 + myrow] + bhh[2048 + myrow];
    const float bg = bih[4096 + myrow] + bhh[4096 + myrow];
    const float bo = bih[6144 + myrow] + bhh[6144 + myrow];
    float c_state = c0[myrow];

    // publish h0 slice with tag 0 (parity 0)
    if (q == 0 && lane < 4) {
        float a = h0[hb + lane * 2], b2 = h0[hb + lane * 2 + 1];
        unsigned long long v = ((unsigned long long)packbf(a, b2) << 32);
        __hip_atomic_store(&hbuf[b * 4 + lane], v, __ATOMIC_RELAXED, __HIP_MEMORY_SCOPE_AGENT);
    }

    // prefetch x_0: thread tid owns x pair tid (cols 2*tid, 2*tid+1)
    float2 xv = ((const float2*)seq)[tid];
    int gave_up = 0;

    for (int s = 1; s <= 8192; s++) {
        const int t = s - 1, bs = t & 1;
        // stage x_t into parity buffer (safe vs step t-2 readers: B1 of t-1 ordered them)
        v_stage[bs][tid] = packbf(xv.x, xv.y);
        // prefetch x_{t+1} (independent of h; hides L2/L3 latency)
        if (s < 8192) xv = ((const float2*)(seq + (size_t)s * 512))[tid];

        // ---- 2-deep pipelined spin: wave q owns h pairs [256q, 256q+256) ----
        if (!gave_up) {
            const unsigned long long* hp = hbuf + ((t & 1) << 10) + q * 256 + lane;
            uint32_t* vs = &v_stage[bs][256 + q * 256 + lane];
            const uint32_t want = (uint32_t)t;
            unsigned long long a0 = ALOAD(&hp[0]), a1 = ALOAD(&hp[64]),
                               a2 = ALOAD(&hp[128]), a3 = ALOAD(&hp[192]);
            int tries = 0;
            for (;;) {
                // issue sweep B while checking sweep A
                unsigned long long b0 = ALOAD(&hp[0]), b1 = ALOAD(&hp[64]),
                                   b2 = ALOAD(&hp[128]), b3 = ALOAD(&hp[192]);
                vs[0]   = (uint32_t)(a0 >> 32);  // idempotent: payload fixed once tag matches
                vs[64]  = (uint32_t)(a1 >> 32);
                vs[128] = (uint32_t)(a2 >> 32);
                vs[192] = (uint32_t)(a3 >> 32);
                int ok = ((uint32_t)a0 == want) & ((uint32_t)a1 == want) &
                         ((uint32_t)a2 == want) & ((uint32_t)a3 == want);
                if (__all(ok)) break;
                a0 = ALOAD(&hp[0]); a1 = ALOAD(&hp[64]);
                a2 = ALOAD(&hp[128]); a3 = ALOAD(&hp[192]);
                vs[0]   = (uint32_t)(b0 >> 32);
                vs[64]  = (uint32_t)(b1 >> 32);
                vs[128] = (uint32_t)(b2 >> 32);
                vs[192] = (uint32_t)(b3 >> 32);
                ok = ((uint32_t)b0 == want) & ((uint32_t)b1 == want) &
                     ((uint32_t)b2 == want) & ((uint32_t)b3 == want);
                if (__all(ok)) break;
                if (++tries > (1 << 17)) { gave_up = 1; break; }  // diagnostic fuse
            }
        }
        __syncthreads();  // B1: v_stage[bs] ready (the ONLY barrier per step)

        // ---- dot: 8 combos (4 gates x 2 rows) x 20 pairs per lane ----
        float acc[8] = {0.f, 0.f, 0.f, 0.f, 0.f, 0.f, 0.f, 0.f};
#pragma unroll
        for (int k = 0; k < 20; k++) {
            uint32_t hv = v_stage[bs][k * 64 + lane];
#pragma unroll
            for (int c = 0; c < 8; c++) acc[c] = dot2bf(w[c * 20 + k], hv, acc[c]);
        }

        // ---- fold 8 accs -> 1 (3 stages) + 3 sum stages; lane L holds combo
        // c(L&7) = 4*(L&1) + 2*((L>>1)&1) + ((L>>2)&1), replicated every 8 lanes ----
#pragma unroll
        for (int j = 0; j < 4; j++) {  // d=1: 8 -> 4
            float lo = acc[j], hi = acc[j + 4];
            float sel = (lane & 1) ? lo : hi;
            float got = __shfl_xor(sel, 1, 64);
            acc[j] = ((lane & 1) ? hi : lo) + got;
        }
#pragma unroll
        for (int j = 0; j < 2; j++) {  // d=2: 4 -> 2
            float lo = acc[j], hi = acc[j + 2];
            float sel = (lane & 2) ? lo : hi;
            float got = __shfl_xor(sel, 2, 64);
            acc[j] = ((lane & 2) ? hi : lo) + got;
        }
        {  // d=4: 2 -> 1
            float lo = acc[0], hi = acc[1];
            float sel = (lane & 4) ? lo : hi;
            float got = __shfl_xor(sel, 4, 64);
            acc[0] = ((lane & 4) ? hi : lo) + got;
        }
        acc[0] += __shfl_xor(acc[0], 8, 64);
        acc[0] += __shfl_xor(acc[0], 16, 64);
        acc[0] += __shfl_xor(acc[0], 32, 64);

        // combo layout within each 4-lane group (base = lane&~3):
        // base+0: i(row rb), base+1: g, base+2: f, base+3: o  (rb = (lane>>2)&1)
        const int base = lane & ~3;
        float gi = __shfl(acc[0], base, 64);
        float gg = __shfl(acc[0], base + 1, 64);
        float gf = __shfl(acc[0], base + 2, 64);
        float go = __shfl(acc[0], base + 3, 64);
        float i_ = sigm(gi + bi), f_ = sigm(gf + bf_), g_ = tanh_fast(gg + bg), o_ = sigm(go + bo);
        c_state = f_ * c_state + i_ * g_;
        float hval = o_ * tanh_fast(c_state);  // lanes 0-3: row0, lanes 4-7: row1 (replicated)

        float h1 = __shfl(hval, 4, 64);  // row1's h
        if (lane == 0) {
            unsigned long long v = ((unsigned long long)packbf(hval, h1) << 32) | (uint32_t)s;
            __hip_atomic_store(&hbuf[((s & 1) << 10) + b * 4 + q], v,
                               __ATOMIC_RELAXED, __HIP_MEMORY_SCOPE_AGENT);
            if (s == 8192) { hf32[hb + 2 * q] = hval; hf32[hb + 2 * q + 1] = h1; }
        }
    }
}

// ---------------- kernel 2: pred = h_last @ W_lin^T + b_lin ----------------
__global__ __launch_bounds__(256) void final_linear(const float* __restrict__ hf,
                                                    const float* __restrict__ Wlin,
                                                    const float* __restrict__ blin,
                                                    float* __restrict__ out) {
    const int row = blockIdx.x * 4 + (threadIdx.x >> 6);
    const int lane = threadIdx.x & 63;
    float acc = 0.f;
#pragma unroll
    for (int it = 0; it < 8; it++) {
        int c = it * 256 + lane * 4;
        float4 wv = *(const float4*)&Wlin[(size_t)row * 2048 + c];
        float4 hv = *(const float4*)&hf[c];
        acc += wv.x * hv.x + wv.y * hv.y + wv.z * hv.z + wv.w * hv.w;
    }
#pragma unroll
    for (int off = 32; off; off >>= 1) acc += __shfl_xor(acc, off, 64);
    if (lane == 0) out[row] = acc + blin[row];
}

// ---------------- launch ----------------
extern "C" void kernel_launch(void* const* d_in, const int* in_sizes, int n_in,
                              void* d_out, int out_size, void* d_ws, size_t ws_size,
                              hipStream_t stream) {
    const float* seq  = (const float*)d_in[0];
    const float* Wih  = (const float*)d_in[1];
    const float* Whh  = (const float*)d_in[2];
    const float* bih  = (const float*)d_in[3];
    const float* bhh  = (const float*)d_in[4];
    const float* h0   = (const float*)d_in[5];
    const float* c0   = (const float*)d_in[6];
    const float* Wlin = (const float*)d_in[7];
    const float* blin = (const float*)d_in[8];
    float* out = (float*)d_out;

    char* ws = (char*)d_ws;
    unsigned long long* hbuf = (unsigned long long*)ws;  // 2*1024*8 = 16 KiB
    float* hf32 = (float*)(ws + 16384);                  // 8 KiB

    init_hbuf<<<8, 256, 0, stream>>>(hbuf);
    lstm_persist<<<256, 256, 0, stream>>>(seq, Wih, Whh, bih, bhh, h0, c0, hbuf, hf32);
    final_linear<<<128, 256, 0, stream>>>(hf32, Wlin, blin, out);
}